// Round 4
// baseline (788.571 us; speedup 1.0000x reference)
//
#include <hip/hip_runtime.h>

#define NN 100000
#define NE 1600000
#define FIN 32
#define FHID 64

#define CLB 7                                   // log2(nodes per bucket)
#define BN (1 << CLB)                           // 128 nodes / bucket
#define NB ((NN + BN - 1) / BN)                 // 782 buckets
#define NDB 512                                 // distributor blocks
#define CHUNK ((NE + NDB - 1) / NDB)            // 3125 edges / distributor block
#define NSC (NB * NDB)                          // 400384 scan elements (= 391*1024)
#define SCAN_B 1024
#define SCAN_NB ((NSC + SCAN_B - 1) / SCAN_B)   // 391

// ---------- pass 1: per-(bucket, block) histogram, transposed layout ----------
__global__ void k_dcount(const int* __restrict__ col, int* __restrict__ hist_g) {
    __shared__ int h[NB];
    for (int i = threadIdx.x; i < NB; i += blockDim.x) h[i] = 0;
    __syncthreads();
    int beg = blockIdx.x * CHUNK, end = min(beg + CHUNK, NE);
    for (int e = beg + threadIdx.x; e < end; e += blockDim.x)
        atomicAdd(&h[col[e] >> CLB], 1);
    __syncthreads();
    for (int i = threadIdx.x; i < NB; i += blockDim.x)
        hist_g[i * NDB + blockIdx.x] = h[i];   // bucket-major: linear scan = bases
}

// ---------- exclusive scan over NSC ints (3 kernels) ----------
__global__ void k_scan1(const int* __restrict__ in, int* __restrict__ out,
                        int* __restrict__ bsum) {
    __shared__ int s[SCAN_B];
    int i = blockIdx.x * SCAN_B + threadIdx.x;
    int v = (i < NSC) ? in[i] : 0;
    s[threadIdx.x] = v;
    __syncthreads();
    for (int o = 1; o < SCAN_B; o <<= 1) {
        int t = (threadIdx.x >= o) ? s[threadIdx.x - o] : 0;
        __syncthreads();
        s[threadIdx.x] += t;
        __syncthreads();
    }
    if (i < NSC) out[i] = s[threadIdx.x] - v;  // exclusive
    if (threadIdx.x == SCAN_B - 1) bsum[blockIdx.x] = s[SCAN_B - 1];
}

__global__ void k_scan2(int* __restrict__ bsum) {   // 1 block, 512 threads
    __shared__ int s[512];
    int v = (threadIdx.x < SCAN_NB) ? bsum[threadIdx.x] : 0;
    s[threadIdx.x] = v;
    __syncthreads();
    for (int o = 1; o < 512; o <<= 1) {
        int t = (threadIdx.x >= o) ? s[threadIdx.x - o] : 0;
        __syncthreads();
        s[threadIdx.x] += t;
        __syncthreads();
    }
    if (threadIdx.x < SCAN_NB) bsum[threadIdx.x] = s[threadIdx.x] - v;  // exclusive
}

__global__ void k_scan3(int* __restrict__ out, const int* __restrict__ bsum) {
    int i = blockIdx.x * blockDim.x + threadIdx.x;
    if (i < NSC) out[i] += bsum[i >> 10];
}

// ---------- pass 2: write records at deterministic bases (no global atomics) ----
// record = ((col_local << 17) | src, ew)
__global__ void k_dwrite(const int* __restrict__ row, const int* __restrict__ col,
                         const float* __restrict__ ew, const int* __restrict__ base_g,
                         uint2* __restrict__ rec) {
    __shared__ int rk[NB];
    __shared__ int bl[NB];
    for (int i = threadIdx.x; i < NB; i += blockDim.x) {
        rk[i] = 0;
        bl[i] = base_g[i * NDB + blockIdx.x];
    }
    __syncthreads();
    int beg = blockIdx.x * CHUNK, end = min(beg + CHUNK, NE);
    for (int e = beg + threadIdx.x; e < end; e += blockDim.x) {
        int c = col[e];
        int bk = c >> CLB;
        int r = atomicAdd(&rk[bk], 1);          // LDS rank
        unsigned pack = ((unsigned)(c & (BN - 1)) << 17) | (unsigned)row[e];
        rec[bl[bk] + r] = make_uint2(pack, __float_as_uint(ew[e]));
    }
}

// ---------- per-bucket degree -> dinv (replaces global-atomic histogram) ------
__global__ void k_deg(const int* __restrict__ base_g, const uint2* __restrict__ rec,
                      float* __restrict__ dinv) {
    __shared__ float dg[BN];
    int b = blockIdx.x;
    for (int i = threadIdx.x; i < BN; i += blockDim.x) dg[i] = 0.0f;
    __syncthreads();
    int beg = base_g[b * NDB];
    int end = (b == NB - 1) ? NE : base_g[(b + 1) * NDB];
    for (int j = beg + threadIdx.x; j < end; j += blockDim.x) {
        uint2 p = rec[j];
        atomicAdd(&dg[p.x >> 17], __uint_as_float(p.y));
    }
    __syncthreads();
    int node = b * BN + threadIdx.x;
    if (threadIdx.x < BN && node < NN)
        dinv[node] = rsqrtf(1.0f + dg[threadIdx.x]);   // self-loop weight 1
}

// ---------- layer-1 aggregation + fused GEMM1 + bias + relu  ->  h ------------
// blockDim = 512 (16 half-waves); acc[128][32] in LDS, LDS float atomics.
__global__ __launch_bounds__(512) void k_agg1f(
        const int* __restrict__ base_g, const uint2* __restrict__ rec,
        const float* __restrict__ x, const float* __restrict__ dinv,
        const float* __restrict__ W1, const float* __restrict__ b1,
        float* __restrict__ h) {
    __shared__ float acc[BN * FIN];    // 16 KB
    __shared__ float sW[FIN * FHID];   // 8 KB
    int tid = threadIdx.x;
    for (int i = tid; i < BN * FIN; i += 512) acc[i] = 0.0f;
    for (int i = tid; i < FIN * FHID; i += 512) sW[i] = W1[i];
    __syncthreads();
    int b = blockIdx.x;
    int beg = base_g[b * NDB];
    int end = (b == NB - 1) ? NE : base_g[(b + 1) * NDB];
    int f = tid & 31;
    auto body = [&](int j) {
        uint2 p = rec[j];
        unsigned src = p.x & 0x1FFFFu;
        unsigned cl = p.x >> 17;
        float w = __uint_as_float(p.y) * dinv[src];
        atomicAdd(&acc[cl * FIN + f], w * x[(size_t)src * FIN + f]);
    };
    int j = beg + (tid >> 5);
    for (; j + 48 < end; j += 64) { body(j); body(j + 16); body(j + 32); body(j + 48); }
    for (; j < end; j += 16) body(j);
    __syncthreads();
    // epilogue A: pre[n][k] = dinv*(acc + dinv*x[n][k])  (in place)
    int node0 = b * BN;
    for (int idx = tid; idx < BN * FIN; idx += 512) {
        int n = idx >> 5, k = idx & 31;
        int node = node0 + n;
        if (node < NN) {
            float di = dinv[node];
            acc[idx] = di * fmaf(di, x[(size_t)node * FIN + k], acc[idx]);
        }
    }
    __syncthreads();
    // epilogue B: h[node][o] = relu(sum_k pre[k]*W1[k][o] + b1[o])
    int o = tid & 63;
    float bia = b1[o];
    for (int n = tid >> 6; n < BN; n += 8) {
        int node = node0 + n;
        if (node >= NN) break;
        float s = bia;
#pragma unroll
        for (int k = 0; k < FIN; ++k)
            s = fmaf(acc[n * FIN + k], sW[k * FHID + o], s);
        h[(size_t)node * FHID + o] = s > 0.0f ? s : 0.0f;
    }
}

// ---------- layer-2 aggregation + bias + relu  ->  out ------------------------
__global__ __launch_bounds__(512) void k_agg2(
        const int* __restrict__ base_g, const uint2* __restrict__ rec,
        const float* __restrict__ hw, const float* __restrict__ dinv,
        const float* __restrict__ b2, float* __restrict__ out) {
    __shared__ float acc[BN * FIN];    // 16 KB
    int tid = threadIdx.x;
    for (int i = tid; i < BN * FIN; i += 512) acc[i] = 0.0f;
    __syncthreads();
    int b = blockIdx.x;
    int beg = base_g[b * NDB];
    int end = (b == NB - 1) ? NE : base_g[(b + 1) * NDB];
    int f = tid & 31;
    auto body = [&](int j) {
        uint2 p = rec[j];
        unsigned src = p.x & 0x1FFFFu;
        unsigned cl = p.x >> 17;
        float w = __uint_as_float(p.y) * dinv[src];
        atomicAdd(&acc[cl * FIN + f], w * hw[(size_t)src * FIN + f]);
    };
    int j = beg + (tid >> 5);
    for (; j + 48 < end; j += 64) { body(j); body(j + 16); body(j + 32); body(j + 48); }
    for (; j < end; j += 16) body(j);
    __syncthreads();
    int node0 = b * BN;
    for (int idx = tid; idx < BN * FIN; idx += 512) {
        int n = idx >> 5, k = idx & 31;
        int node = node0 + n;
        if (node < NN) {
            float di = dinv[node];
            float v = di * fmaf(di, hw[(size_t)node * FIN + k], acc[idx]) + b2[k];
            out[(size_t)node * FIN + k] = v > 0.0f ? v : 0.0f;
        }
    }
}

// ---------- small dense GEMM (layer 2: 64 -> 32), W staged in LDS -------------
template<int IN, int OUT>
__global__ void k_gemm(const float* __restrict__ X, const float* __restrict__ W,
                       float* __restrict__ Y) {
    __shared__ float sW[IN * OUT];
    for (int i = threadIdx.x; i < IN * OUT; i += blockDim.x) sW[i] = W[i];
    __syncthreads();
    int idx = blockIdx.x * blockDim.x + threadIdx.x;
    if (idx >= NN * OUT) return;
    int n = idx / OUT;
    int of = idx - n * OUT;
    const float* xr = X + (size_t)n * IN;
    float acc = 0.0f;
#pragma unroll
    for (int k = 0; k < IN; ++k) acc = fmaf(xr[k], sW[k * OUT + of], acc);
    Y[idx] = acc;
}

extern "C" void kernel_launch(void* const* d_in, const int* in_sizes, int n_in,
                              void* d_out, int out_size, void* d_ws, size_t ws_size,
                              hipStream_t stream) {
    const float* x  = (const float*)d_in[0];
    const int*   ei = (const int*)d_in[1];
    const float* ea = (const float*)d_in[2];
    const float* W1 = (const float*)d_in[3];
    const float* b1 = (const float*)d_in[4];
    const float* W2 = (const float*)d_in[5];
    const float* b2 = (const float*)d_in[6];
    float* out = (float*)d_out;

    const int* row = ei;        // edge_index[0]
    const int* col = ei + NE;   // edge_index[1]

    // workspace layout (8B-aligned first)
    char* w = (char*)d_ws;
    uint2* rec    = (uint2*)w;                          // NE * 8B
    float* h      = (float*)(w + (size_t)NE * 8);       // NN*FHID
    float* hw2    = h + (size_t)NN * FHID;              // NN*FIN
    float* dinv   = hw2 + (size_t)NN * FIN;             // NN
    int*   hist_g = (int*)(dinv + NN);                  // NSC
    int*   scng   = hist_g + NSC;                       // NSC
    int*   bsum   = scng + NSC;                         // 512

    auto cdiv = [](long long a, int b) { return (int)((a + b - 1) / b); };

    // independent: edge_attr passthrough
    hipMemcpyAsync(out + (size_t)NN * FIN, ea, sizeof(float) * (size_t)NE,
                   hipMemcpyDeviceToDevice, stream);

    // counting-sort CSR-free bucket build (no global atomics)
    k_dcount<<<NDB, 256, 0, stream>>>(col, hist_g);
    k_scan1<<<SCAN_NB, SCAN_B, 0, stream>>>(hist_g, scng, bsum);
    k_scan2<<<1, 512, 0, stream>>>(bsum);
    k_scan3<<<cdiv(NSC, 256), 256, 0, stream>>>(scng, bsum);
    k_dwrite<<<NDB, 256, 0, stream>>>(row, col, ea, scng, rec);

    // degree -> dinv (per-bucket, LDS)
    k_deg<<<NB, 256, 0, stream>>>(scng, rec, dinv);

    // layer 1: h = relu((A x) W1 + b1)  — agg + GEMM fused
    k_agg1f<<<NB, 512, 0, stream>>>(scng, rec, x, dinv, W1, b1, h);

    // layer 2: out = relu(A (h W2) + b2)
    k_gemm<FHID, FIN><<<cdiv((long long)NN * FIN, 256), 256, 0, stream>>>(h, W2, hw2);
    k_agg2<<<NB, 512, 0, stream>>>(scng, rec, hw2, dinv, b2, out);
}

// Round 5
// 239.764 us; speedup vs baseline: 3.2889x; 3.2889x over previous
//
#include <hip/hip_runtime.h>

#define NN 100000
#define NE 1600000
#define FIN 32
#define FHID 64

#define CLB 7                                   // log2(nodes per bucket)
#define BN (1 << CLB)                           // 128 nodes / bucket
#define NB ((NN + BN - 1) / BN)                 // 782 buckets
#define NDB 256                                 // distributor blocks
#define CHUNK ((NE + NDB - 1) / NDB)            // 6250 edges / distributor block
#define NSC (NB * NDB)                          // 200192 scan elements
#define SCAN_B 1024
#define SCAN_NB ((NSC + SCAN_B - 1) / SCAN_B)   // 196

#define LGKM0 asm volatile("s_waitcnt lgkmcnt(0)" ::: "memory")

// ---------- pass 1: per-(bucket, block) histogram, bucket-major layout --------
__global__ void k_dcount(const int* __restrict__ col, int* __restrict__ hist_g) {
    __shared__ int hc[NB];
    for (int i = threadIdx.x; i < NB; i += blockDim.x) hc[i] = 0;
    __syncthreads();
    int beg = blockIdx.x * CHUNK, end = min(beg + CHUNK, NE);
    for (int e = beg + threadIdx.x; e < end; e += blockDim.x)
        atomicAdd(&hc[col[e] >> CLB], 1);
    __syncthreads();
    for (int i = threadIdx.x; i < NB; i += blockDim.x)
        hist_g[i * NDB + blockIdx.x] = hc[i];
}

// ---------- exclusive scan over NSC ints (3 kernels) ----------
__global__ void k_scan1(const int* __restrict__ in, int* __restrict__ out,
                        int* __restrict__ bsum) {
    __shared__ int s[SCAN_B];
    int i = blockIdx.x * SCAN_B + threadIdx.x;
    int v = (i < NSC) ? in[i] : 0;
    s[threadIdx.x] = v;
    __syncthreads();
    for (int o = 1; o < SCAN_B; o <<= 1) {
        int t = (threadIdx.x >= o) ? s[threadIdx.x - o] : 0;
        __syncthreads();
        s[threadIdx.x] += t;
        __syncthreads();
    }
    if (i < NSC) out[i] = s[threadIdx.x] - v;  // exclusive
    if (threadIdx.x == SCAN_B - 1) bsum[blockIdx.x] = s[SCAN_B - 1];
}

__global__ void k_scan2(int* __restrict__ bsum) {   // 1 block, 256 threads
    __shared__ int s[256];
    int v = (threadIdx.x < SCAN_NB) ? bsum[threadIdx.x] : 0;
    s[threadIdx.x] = v;
    __syncthreads();
    for (int o = 1; o < 256; o <<= 1) {
        int t = (threadIdx.x >= o) ? s[threadIdx.x - o] : 0;
        __syncthreads();
        s[threadIdx.x] += t;
        __syncthreads();
    }
    if (threadIdx.x < SCAN_NB) bsum[threadIdx.x] = s[threadIdx.x] - v;  // exclusive
}

__global__ void k_scan3(int* __restrict__ out, const int* __restrict__ bsum) {
    int i = blockIdx.x * blockDim.x + threadIdx.x;
    if (i < NSC) out[i] += bsum[i >> 10];
}

// ---------- pass 2: write bucketed records (no global atomics) ----------------
// record = ((col_local << 17) | src, ew_bits)
__global__ void k_dwrite(const int* __restrict__ row, const int* __restrict__ col,
                         const float* __restrict__ ew, const int* __restrict__ base_g,
                         uint2* __restrict__ rec0) {
    __shared__ int rk[NB];
    __shared__ int bl[NB];
    for (int i = threadIdx.x; i < NB; i += blockDim.x) {
        rk[i] = 0;
        bl[i] = base_g[i * NDB + blockIdx.x];
    }
    __syncthreads();
    int beg = blockIdx.x * CHUNK, end = min(beg + CHUNK, NE);
    for (int e = beg + threadIdx.x; e < end; e += blockDim.x) {
        int c = col[e];
        int bk = c >> CLB;
        int r = atomicAdd(&rk[bk], 1);
        unsigned pack = ((unsigned)(c & (BN - 1)) << 17) | (unsigned)row[e];
        rec0[bl[bk] + r] = make_uint2(pack, __float_as_uint(ew[e]));
    }
}

// ---------- per-bucket sort -> exact per-node CSR + degree/dinv ---------------
__global__ void k_bsort(const int* __restrict__ base_g, const uint2* __restrict__ rec0,
                        uint2* __restrict__ csr, int* __restrict__ rowptr,
                        float* __restrict__ dinv) {
    __shared__ int cnt[BN];
    __shared__ int bas[BN];
    __shared__ int cur[BN];
    __shared__ float dg[BN];
    int tid = threadIdx.x;
    int b = blockIdx.x;
    int beg = base_g[b * NDB];
    int end = (b == NB - 1) ? NE : base_g[(b + 1) * NDB];
    if (tid < BN) { cnt[tid] = 0; dg[tid] = 0.0f; }
    __syncthreads();
    for (int j = beg + tid; j < end; j += blockDim.x) {
        uint2 p = rec0[j];
        int cl = p.x >> 17;
        atomicAdd(&cnt[cl], 1);
        atomicAdd(&dg[cl], __uint_as_float(p.y));
    }
    __syncthreads();
    int v0 = (tid < BN) ? cnt[tid] : 0;
    __syncthreads();
    for (int o = 1; o < BN; o <<= 1) {               // Hillis-Steele inclusive
        int t = (tid < BN && tid >= o) ? cnt[tid - o] : 0;
        __syncthreads();
        if (tid < BN) cnt[tid] += t;
        __syncthreads();
    }
    if (tid < BN) {
        int excl = cnt[tid] - v0;
        bas[tid] = excl;
        cur[tid] = 0;
        int node = b * BN + tid;
        if (node < NN) {
            rowptr[node] = beg + excl;
            dinv[node] = rsqrtf(1.0f + dg[tid]);     // self-loop weight 1
        }
    }
    if (b == 0 && tid == 0) rowptr[NN] = NE;
    __syncthreads();
    for (int j = beg + tid; j < end; j += blockDim.x) {
        uint2 p = rec0[j];
        int cl = p.x >> 17;
        int r = atomicAdd(&cur[cl], 1);
        csr[beg + bas[cl] + r] = make_uint2(p.x & 0x1FFFFu, p.y);
    }
}

// ---------- x' = dinv * x (fold src-side norm into the operand) ---------------
__global__ void k_scalex(const float* __restrict__ x, const float* __restrict__ dinv,
                         float* __restrict__ xp) {
    int idx = blockIdx.x * blockDim.x + threadIdx.x;   // float4 index
    if (idx >= NN * (FIN / 4)) return;
    float dn = dinv[idx >> 3];
    float4 v = ((const float4*)x)[idx];
    v.x *= dn; v.y *= dn; v.z *= dn; v.w *= dn;
    ((float4*)xp)[idx] = v;
}

// ---------- layer 1 fused: agg + GEMM1(+b1,relu) + GEMM2 + dinv  -> hw2p ------
// Grid-stride wave-per-node. W1 column + W2 half-column in registers.
// pre/h exchanged through tiny per-wave LDS buffers (intra-wave only).
__global__ __launch_bounds__(256) void k_agg1f(
        const int* __restrict__ rowptr, const uint2* __restrict__ csr,
        const float* __restrict__ xp, const float* __restrict__ dinv,
        const float* __restrict__ W1, const float* __restrict__ b1,
        const float* __restrict__ W2, float* __restrict__ hw2p, int nwaves) {
    __shared__ float pre_lds[4 * FIN];
    __shared__ float hv_lds[4 * FHID];
    int lane = threadIdx.x & 63;
    int ws = threadIdx.x >> 6;          // wave slot in block
    int hh = lane >> 5;
    int f = lane & 31;
    int o = lane;                        // 0..63
    // register-resident weights
    float W1col[FIN];
#pragma unroll
    for (int k = 0; k < FIN; ++k) W1col[k] = W1[k * FHID + o];
    float b1o = b1[o];
    float W2h[FIN];
#pragma unroll
    for (int k = 0; k < FIN; ++k) W2h[k] = W2[(hh * 32 + k) * FIN + f];

    int gw = (blockIdx.x * blockDim.x + threadIdx.x) >> 6;
    for (int n = gw; n < NN; n += nwaves) {
        int beg = rowptr[n], end = rowptr[n + 1];
        float a0 = 0.0f, a1 = 0.0f;
        int j = beg + hh;
        for (; j + 2 < end; j += 4) {
            uint2 e0 = csr[j];
            uint2 e1 = csr[j + 2];
            a0 = fmaf(__uint_as_float(e0.y), xp[(size_t)e0.x * FIN + f], a0);
            a1 = fmaf(__uint_as_float(e1.y), xp[(size_t)e1.x * FIN + f], a1);
        }
        for (; j < end; j += 2) {
            uint2 e = csr[j];
            a0 = fmaf(__uint_as_float(e.y), xp[(size_t)e.x * FIN + f], a0);
        }
        float s = a0 + a1;
        s += __shfl_xor(s, 32, 64);
        float dn = dinv[n];
        float pre = dn * (s + xp[(size_t)n * FIN + f]);   // (A~ x)[n][f]
        pre_lds[ws * FIN + f] = pre;                      // dup write ok
        LGKM0;
        // GEMM1: h_o = relu(b1 + sum_k pre[k] * W1[k][o])
        float hacc = b1o;
#pragma unroll
        for (int i = 0; i < 8; ++i) {
            float4 q = *(const float4*)&pre_lds[ws * FIN + 4 * i];
            hacc = fmaf(q.x, W1col[4 * i + 0], hacc);
            hacc = fmaf(q.y, W1col[4 * i + 1], hacc);
            hacc = fmaf(q.z, W1col[4 * i + 2], hacc);
            hacc = fmaf(q.w, W1col[4 * i + 3], hacc);
        }
        hacc = hacc > 0.0f ? hacc : 0.0f;
        hv_lds[ws * FHID + o] = hacc;
        LGKM0;
        // GEMM2 (halves split o-range): hw2'[n][f] = dn * sum_o h_o W2[o][f]
        float part = 0.0f;
#pragma unroll
        for (int i = 0; i < 8; ++i) {
            float4 q = *(const float4*)&hv_lds[ws * FHID + hh * 32 + 4 * i];
            part = fmaf(q.x, W2h[4 * i + 0], part);
            part = fmaf(q.y, W2h[4 * i + 1], part);
            part = fmaf(q.z, W2h[4 * i + 2], part);
            part = fmaf(q.w, W2h[4 * i + 3], part);
        }
        part += __shfl_xor(part, 32, 64);
        if (hh == 0) hw2p[(size_t)n * FIN + f] = dn * part;
    }
}

// ---------- layer 2 aggregation + bias + relu -> out --------------------------
__global__ void k_agg2(const int* __restrict__ rowptr, const uint2* __restrict__ csr,
                       const float* __restrict__ hw2p, const float* __restrict__ dinv,
                       const float* __restrict__ b2, float* __restrict__ out) {
    int wv = (blockIdx.x * blockDim.x + threadIdx.x) >> 6;
    if (wv >= NN) return;
    int lane = threadIdx.x & 63;
    int hh = lane >> 5;
    int f = lane & 31;
    int beg = rowptr[wv], end = rowptr[wv + 1];
    float a0 = 0.0f, a1 = 0.0f;
    int j = beg + hh;
    for (; j + 2 < end; j += 4) {
        uint2 e0 = csr[j];
        uint2 e1 = csr[j + 2];
        a0 = fmaf(__uint_as_float(e0.y), hw2p[(size_t)e0.x * FIN + f], a0);
        a1 = fmaf(__uint_as_float(e1.y), hw2p[(size_t)e1.x * FIN + f], a1);
    }
    for (; j < end; j += 2) {
        uint2 e = csr[j];
        a0 = fmaf(__uint_as_float(e.y), hw2p[(size_t)e.x * FIN + f], a0);
    }
    float s = a0 + a1;
    s += __shfl_xor(s, 32, 64);
    if (hh == 0) {
        float dn = dinv[wv];
        float v = dn * (s + hw2p[(size_t)wv * FIN + f]) + b2[f];
        out[(size_t)wv * FIN + f] = v > 0.0f ? v : 0.0f;
    }
}

extern "C" void kernel_launch(void* const* d_in, const int* in_sizes, int n_in,
                              void* d_out, int out_size, void* d_ws, size_t ws_size,
                              hipStream_t stream) {
    const float* x  = (const float*)d_in[0];
    const int*   ei = (const int*)d_in[1];
    const float* ea = (const float*)d_in[2];
    const float* W1 = (const float*)d_in[3];
    const float* b1 = (const float*)d_in[4];
    const float* W2 = (const float*)d_in[5];
    const float* b2 = (const float*)d_in[6];
    float* out = (float*)d_out;

    const int* row = ei;        // edge_index[0]
    const int* col = ei + NE;   // edge_index[1]

    // workspace layout (~54 MB)
    char* w = (char*)d_ws;
    uint2* rec0  = (uint2*)w;                            // NE*8
    uint2* csr   = rec0 + NE;                            // NE*8
    float* xp    = (float*)(csr + NE);                   // NN*FIN
    float* hw2p  = xp + (size_t)NN * FIN;                // NN*FIN
    float* dinv  = hw2p + (size_t)NN * FIN;              // NN
    int*   rowptr = (int*)(dinv + NN);                   // NN+1
    int*   hist_g = rowptr + NN + 1;                     // NSC
    int*   scng   = hist_g + NSC;                        // NSC
    int*   bsum   = scng + NSC;                          // 256

    auto cdiv = [](long long a, int b) { return (int)((a + b - 1) / b); };

    // independent: edge_attr passthrough
    hipMemcpyAsync(out + (size_t)NN * FIN, ea, sizeof(float) * (size_t)NE,
                   hipMemcpyDeviceToDevice, stream);

    // deterministic counting-sort build (no global atomics)
    k_dcount<<<NDB, 256, 0, stream>>>(col, hist_g);
    k_scan1<<<SCAN_NB, SCAN_B, 0, stream>>>(hist_g, scng, bsum);
    k_scan2<<<1, 256, 0, stream>>>(bsum);
    k_scan3<<<cdiv(NSC, 256), 256, 0, stream>>>(scng, bsum);
    k_dwrite<<<NDB, 256, 0, stream>>>(row, col, ea, scng, rec0);
    k_bsort<<<NB, 256, 0, stream>>>(scng, rec0, csr, rowptr, dinv);

    // fold src-side norm into x
    k_scalex<<<cdiv((long long)NN * (FIN / 4), 256), 256, 0, stream>>>(x, dinv, xp);

    // layer 1 fused (agg + GEMM1 + GEMM2 + dst scale) -> hw2p
    const int A1_BLOCKS = 2048;
    k_agg1f<<<A1_BLOCKS, 256, 0, stream>>>(rowptr, csr, xp, dinv, W1, b1, W2,
                                           hw2p, A1_BLOCKS * 4);

    // layer 2 aggregation -> out
    k_agg2<<<cdiv((long long)NN * 64, 256), 256, 0, stream>>>(
        rowptr, csr, hw2p, dinv, b2, out);
}

// Round 6
// 196.485 us; speedup vs baseline: 4.0134x; 1.2203x over previous
//
#include <hip/hip_runtime.h>

#define NN 100000
#define NE 1600000
#define FIN 32
#define FHID 64

#define CLB 7                                   // log2(nodes per bucket)
#define BN (1 << CLB)                           // 128 nodes / bucket
#define NB ((NN + BN - 1) / BN)                 // 782 buckets
#define NDB 256                                 // distributor blocks
#define CHUNK ((NE + NDB - 1) / NDB)            // 6250 edges / distributor block
#define NSC (NB * NDB)                          // 200192 scan elements
#define SCAN_B 1024
#define SCAN_NB ((NSC + SCAN_B - 1) / SCAN_B)   // 196

#define LGKM0 asm volatile("s_waitcnt lgkmcnt(0)" ::: "memory")

__device__ __forceinline__ float lo16(unsigned g) {
    return __uint_as_float(g << 16);
}
__device__ __forceinline__ float hi16(unsigned g) {
    return __uint_as_float(g & 0xFFFF0000u);
}
__device__ __forceinline__ unsigned pack_bf16(float a, float b) {
    unsigned ua = __float_as_uint(a);
    unsigned ub = __float_as_uint(b);
    ua += 0x7FFFu + ((ua >> 16) & 1u);          // RNE
    ub += 0x7FFFu + ((ub >> 16) & 1u);
    return (ua >> 16) | (ub & 0xFFFF0000u);
}

// ---------- pass 1: per-(bucket, block) histogram, bucket-major layout --------
__global__ void k_dcount(const int* __restrict__ col, int* __restrict__ hist_g) {
    __shared__ int hc[NB];
    for (int i = threadIdx.x; i < NB; i += blockDim.x) hc[i] = 0;
    __syncthreads();
    int beg = blockIdx.x * CHUNK, end = min(beg + CHUNK, NE);
    for (int e = beg + threadIdx.x; e < end; e += blockDim.x)
        atomicAdd(&hc[col[e] >> CLB], 1);
    __syncthreads();
    for (int i = threadIdx.x; i < NB; i += blockDim.x)
        hist_g[i * NDB + blockIdx.x] = hc[i];
}

// ---------- exclusive scan over NSC ints (3 kernels) ----------
__global__ void k_scan1(const int* __restrict__ in, int* __restrict__ out,
                        int* __restrict__ bsum) {
    __shared__ int s[SCAN_B];
    int i = blockIdx.x * SCAN_B + threadIdx.x;
    int v = (i < NSC) ? in[i] : 0;
    s[threadIdx.x] = v;
    __syncthreads();
    for (int o = 1; o < SCAN_B; o <<= 1) {
        int t = (threadIdx.x >= o) ? s[threadIdx.x - o] : 0;
        __syncthreads();
        s[threadIdx.x] += t;
        __syncthreads();
    }
    if (i < NSC) out[i] = s[threadIdx.x] - v;  // exclusive
    if (threadIdx.x == SCAN_B - 1) bsum[blockIdx.x] = s[SCAN_B - 1];
}

__global__ void k_scan2(int* __restrict__ bsum) {   // 1 block, 256 threads
    __shared__ int s[256];
    int v = (threadIdx.x < SCAN_NB) ? bsum[threadIdx.x] : 0;
    s[threadIdx.x] = v;
    __syncthreads();
    for (int o = 1; o < 256; o <<= 1) {
        int t = (threadIdx.x >= o) ? s[threadIdx.x - o] : 0;
        __syncthreads();
        s[threadIdx.x] += t;
        __syncthreads();
    }
    if (threadIdx.x < SCAN_NB) bsum[threadIdx.x] = s[threadIdx.x] - v;  // exclusive
}

__global__ void k_scan3(int* __restrict__ out, const int* __restrict__ bsum) {
    int i = blockIdx.x * blockDim.x + threadIdx.x;
    if (i < NSC) out[i] += bsum[i >> 10];
}

// ---------- pass 2: write bucketed records (no global atomics) ----------------
// record = ((col_local << 17) | src, ew_bits)
__global__ void k_dwrite(const int* __restrict__ row, const int* __restrict__ col,
                         const float* __restrict__ ew, const int* __restrict__ base_g,
                         uint2* __restrict__ rec0) {
    __shared__ int rk[NB];
    __shared__ int bl[NB];
    for (int i = threadIdx.x; i < NB; i += blockDim.x) {
        rk[i] = 0;
        bl[i] = base_g[i * NDB + blockIdx.x];
    }
    __syncthreads();
    int beg = blockIdx.x * CHUNK, end = min(beg + CHUNK, NE);
    for (int e = beg + threadIdx.x; e < end; e += blockDim.x) {
        int c = col[e];
        int bk = c >> CLB;
        int r = atomicAdd(&rk[bk], 1);
        unsigned pack = ((unsigned)(c & (BN - 1)) << 17) | (unsigned)row[e];
        rec0[bl[bk] + r] = make_uint2(pack, __float_as_uint(ew[e]));
    }
}

// ---------- per-bucket sort -> exact per-node CSR + degree/dinv ---------------
__global__ void k_bsort(const int* __restrict__ base_g, const uint2* __restrict__ rec0,
                        uint2* __restrict__ csr, int* __restrict__ rowptr,
                        float* __restrict__ dinv) {
    __shared__ int cnt[BN];
    __shared__ int bas[BN];
    __shared__ int cur[BN];
    __shared__ float dg[BN];
    int tid = threadIdx.x;
    int b = blockIdx.x;
    int beg = base_g[b * NDB];
    int end = (b == NB - 1) ? NE : base_g[(b + 1) * NDB];
    if (tid < BN) { cnt[tid] = 0; dg[tid] = 0.0f; }
    __syncthreads();
    for (int j = beg + tid; j < end; j += blockDim.x) {
        uint2 p = rec0[j];
        int cl = p.x >> 17;
        atomicAdd(&cnt[cl], 1);
        atomicAdd(&dg[cl], __uint_as_float(p.y));
    }
    __syncthreads();
    int v0 = (tid < BN) ? cnt[tid] : 0;
    __syncthreads();
    for (int o = 1; o < BN; o <<= 1) {               // Hillis-Steele inclusive
        int t = (tid < BN && tid >= o) ? cnt[tid - o] : 0;
        __syncthreads();
        if (tid < BN) cnt[tid] += t;
        __syncthreads();
    }
    if (tid < BN) {
        int excl = cnt[tid] - v0;
        bas[tid] = excl;
        cur[tid] = 0;
        int node = b * BN + tid;
        if (node < NN) {
            rowptr[node] = beg + excl;
            dinv[node] = rsqrtf(1.0f + dg[tid]);     // self-loop weight 1
        }
    }
    if (b == 0 && tid == 0) rowptr[NN] = NE;
    __syncthreads();
    for (int j = beg + tid; j < end; j += blockDim.x) {
        uint2 p = rec0[j];
        int cl = p.x >> 17;
        int r = atomicAdd(&cur[cl], 1);
        csr[beg + bas[cl] + r] = make_uint2(p.x & 0x1FFFFu, p.y);
    }
}

// ---------- xp = bf16x2-packed dinv*x ----------------------------------------
__global__ void k_scalex(const float* __restrict__ x, const float* __restrict__ dinv,
                         unsigned* __restrict__ xp) {
    int idx = blockIdx.x * blockDim.x + threadIdx.x;   // pair index
    if (idx >= NN * (FIN / 2)) return;
    float dn = dinv[idx >> 4];
    float2 v = ((const float2*)x)[idx];
    xp[idx] = pack_bf16(v.x * dn, v.y * dn);
}

// ---------- layer 1 fused: agg + GEMM1(+b1,relu) + GEMM2 + dinv  -> hw2p ------
// Wave layout: quarter q = lane>>4 owns edge slot (j = beg+q step 4);
// t = lane&15 owns feature pair (2t, 2t+1) packed bf16x2.
__global__ __launch_bounds__(256) void k_agg1f(
        const int* __restrict__ rowptr, const uint2* __restrict__ csr,
        const unsigned* __restrict__ xp, const float* __restrict__ dinv,
        const float* __restrict__ W1, const float* __restrict__ b1,
        const float* __restrict__ W2, unsigned* __restrict__ hw2p, int nwaves) {
    __shared__ float pre_lds[4 * FIN];
    __shared__ float hv_lds[4 * FHID];
    int lane = threadIdx.x & 63;
    int ws = threadIdx.x >> 6;          // wave slot in block
    int q = lane >> 4;                  // edge slot 0..3
    int t = lane & 15;                  // feature-pair index
    int hh = lane >> 5;
    int f = lane & 31;
    int o = lane;                       // 0..63
    // register-resident weights
    float W1col[FIN];
#pragma unroll
    for (int k = 0; k < FIN; ++k) W1col[k] = W1[k * FHID + o];
    float b1o = b1[o];
    float W2h[FIN];
#pragma unroll
    for (int k = 0; k < FIN; ++k) W2h[k] = W2[(hh * 32 + k) * FIN + f];

    int gw = (blockIdx.x * blockDim.x + threadIdx.x) >> 6;
    for (int n = gw; n < NN; n += nwaves) {
        int beg = rowptr[n], end = rowptr[n + 1];
        float ax0 = 0.0f, ay0 = 0.0f, ax1 = 0.0f, ay1 = 0.0f;
        int j = beg + q;
        for (; j + 4 < end; j += 8) {
            uint2 e0 = csr[j];
            uint2 e1 = csr[j + 4];
            unsigned g0 = xp[(size_t)e0.x * 16 + t];
            unsigned g1 = xp[(size_t)e1.x * 16 + t];
            float w0 = __uint_as_float(e0.y);
            float w1 = __uint_as_float(e1.y);
            ax0 = fmaf(w0, lo16(g0), ax0);
            ay0 = fmaf(w0, hi16(g0), ay0);
            ax1 = fmaf(w1, lo16(g1), ax1);
            ay1 = fmaf(w1, hi16(g1), ay1);
        }
        for (; j < end; j += 4) {
            uint2 e = csr[j];
            unsigned g = xp[(size_t)e.x * 16 + t];
            float w = __uint_as_float(e.y);
            ax0 = fmaf(w, lo16(g), ax0);
            ay0 = fmaf(w, hi16(g), ay0);
        }
        ax0 += ax1; ay0 += ay1;
        // cross-quarter reduce (every lane ends with totals for its pair t)
        ax0 += __shfl_xor(ax0, 32, 64);
        ay0 += __shfl_xor(ay0, 32, 64);
        ax0 += __shfl_xor(ax0, 16, 64);
        ay0 += __shfl_xor(ay0, 16, 64);
        float dn = dinv[n];
        unsigned gs = xp[(size_t)n * 16 + t];
        float px = dn * (ax0 + lo16(gs));
        float py = dn * (ay0 + hi16(gs));
        ((float2*)pre_lds)[ws * 16 + t] = make_float2(px, py);  // dup write ok
        LGKM0;
        // GEMM1: h_o = relu(b1 + sum_k pre[k] * W1[k][o])
        float hacc = b1o;
#pragma unroll
        for (int i = 0; i < 8; ++i) {
            float4 qd = *(const float4*)&pre_lds[ws * FIN + 4 * i];
            hacc = fmaf(qd.x, W1col[4 * i + 0], hacc);
            hacc = fmaf(qd.y, W1col[4 * i + 1], hacc);
            hacc = fmaf(qd.z, W1col[4 * i + 2], hacc);
            hacc = fmaf(qd.w, W1col[4 * i + 3], hacc);
        }
        hacc = hacc > 0.0f ? hacc : 0.0f;
        hv_lds[ws * FHID + o] = hacc;
        LGKM0;
        // GEMM2 (halves split o-range): v[f] = dn * sum_o h_o W2[o][f]
        float part = 0.0f;
#pragma unroll
        for (int i = 0; i < 8; ++i) {
            float4 qd = *(const float4*)&hv_lds[ws * FHID + hh * 32 + 4 * i];
            part = fmaf(qd.x, W2h[4 * i + 0], part);
            part = fmaf(qd.y, W2h[4 * i + 1], part);
            part = fmaf(qd.z, W2h[4 * i + 2], part);
            part = fmaf(qd.w, W2h[4 * i + 3], part);
        }
        part += __shfl_xor(part, 32, 64);    // all lanes: final v for f=lane&31
        float v = dn * part;
        float vlo = __shfl(v, 2 * t, 64);
        float vhi = __shfl(v, 2 * t + 1, 64);
        if (lane < 16) hw2p[(size_t)n * 16 + lane] = pack_bf16(vlo, vhi);
    }
}

// ---------- layer 2 aggregation + bias + relu -> out --------------------------
__global__ __launch_bounds__(256) void k_agg2(
        const int* __restrict__ rowptr, const uint2* __restrict__ csr,
        const unsigned* __restrict__ hw2p, const float* __restrict__ dinv,
        const float* __restrict__ b2, float* __restrict__ out) {
    int n = (blockIdx.x * blockDim.x + threadIdx.x) >> 6;
    if (n >= NN) return;
    int lane = threadIdx.x & 63;
    int q = lane >> 4;
    int t = lane & 15;
    float2 b2p = ((const float2*)b2)[t];
    int beg = rowptr[n], end = rowptr[n + 1];
    float ax0 = 0.0f, ay0 = 0.0f, ax1 = 0.0f, ay1 = 0.0f;
    int j = beg + q;
    for (; j + 4 < end; j += 8) {
        uint2 e0 = csr[j];
        uint2 e1 = csr[j + 4];
        unsigned g0 = hw2p[(size_t)e0.x * 16 + t];
        unsigned g1 = hw2p[(size_t)e1.x * 16 + t];
        float w0 = __uint_as_float(e0.y);
        float w1 = __uint_as_float(e1.y);
        ax0 = fmaf(w0, lo16(g0), ax0);
        ay0 = fmaf(w0, hi16(g0), ay0);
        ax1 = fmaf(w1, lo16(g1), ax1);
        ay1 = fmaf(w1, hi16(g1), ay1);
    }
    for (; j < end; j += 4) {
        uint2 e = csr[j];
        unsigned g = hw2p[(size_t)e.x * 16 + t];
        float w = __uint_as_float(e.y);
        ax0 = fmaf(w, lo16(g), ax0);
        ay0 = fmaf(w, hi16(g), ay0);
    }
    ax0 += ax1; ay0 += ay1;
    ax0 += __shfl_xor(ax0, 32, 64);
    ay0 += __shfl_xor(ay0, 32, 64);
    ax0 += __shfl_xor(ax0, 16, 64);
    ay0 += __shfl_xor(ay0, 16, 64);
    if (lane < 16) {
        float dn = dinv[n];
        unsigned gs = hw2p[(size_t)n * 16 + t];
        float vx = dn * (ax0 + lo16(gs)) + b2p.x;
        float vy = dn * (ay0 + hi16(gs)) + b2p.y;
        vx = vx > 0.0f ? vx : 0.0f;
        vy = vy > 0.0f ? vy : 0.0f;
        ((float2*)out)[(size_t)n * 16 + t] = make_float2(vx, vy);
    }
}

extern "C" void kernel_launch(void* const* d_in, const int* in_sizes, int n_in,
                              void* d_out, int out_size, void* d_ws, size_t ws_size,
                              hipStream_t stream) {
    const float* x  = (const float*)d_in[0];
    const int*   ei = (const int*)d_in[1];
    const float* ea = (const float*)d_in[2];
    const float* W1 = (const float*)d_in[3];
    const float* b1 = (const float*)d_in[4];
    const float* W2 = (const float*)d_in[5];
    const float* b2 = (const float*)d_in[6];
    float* out = (float*)d_out;

    const int* row = ei;        // edge_index[0]
    const int* col = ei + NE;   // edge_index[1]

    // workspace layout (~41 MB)
    char* w = (char*)d_ws;
    uint2* rec0     = (uint2*)w;                         // NE*8
    uint2* csr      = rec0 + NE;                         // NE*8
    unsigned* xp    = (unsigned*)(csr + NE);             // NN*16 (bf16x2)
    unsigned* hw2p  = xp + (size_t)NN * 16;              // NN*16 (bf16x2)
    float* dinv     = (float*)(hw2p + (size_t)NN * 16);  // NN
    int*   rowptr   = (int*)(dinv + NN);                 // NN+1
    int*   hist_g   = rowptr + NN + 1;                   // NSC
    int*   scng     = hist_g + NSC;                      // NSC
    int*   bsum     = scng + NSC;                        // 256

    auto cdiv = [](long long a, int b) { return (int)((a + b - 1) / b); };

    // independent: edge_attr passthrough
    hipMemcpyAsync(out + (size_t)NN * FIN, ea, sizeof(float) * (size_t)NE,
                   hipMemcpyDeviceToDevice, stream);

    // deterministic counting-sort build (no global atomics)
    k_dcount<<<NDB, 256, 0, stream>>>(col, hist_g);
    k_scan1<<<SCAN_NB, SCAN_B, 0, stream>>>(hist_g, scng, bsum);
    k_scan2<<<1, 256, 0, stream>>>(bsum);
    k_scan3<<<cdiv(NSC, 256), 256, 0, stream>>>(scng, bsum);
    k_dwrite<<<NDB, 256, 0, stream>>>(row, col, ea, scng, rec0);
    k_bsort<<<NB, 256, 0, stream>>>(scng, rec0, csr, rowptr, dinv);

    // fold src-side norm into x, pack bf16x2
    k_scalex<<<cdiv((long long)NN * (FIN / 2), 256), 256, 0, stream>>>(x, dinv, xp);

    // layer 1 fused (agg + GEMM1 + GEMM2 + dst scale) -> hw2p (bf16x2)
    const int A1_BLOCKS = 2048;
    k_agg1f<<<A1_BLOCKS, 256, 0, stream>>>(rowptr, csr, xp, dinv, W1, b1, W2,
                                           hw2p, A1_BLOCKS * 4);

    // layer 2 aggregation -> out
    k_agg2<<<cdiv((long long)NN * 64, 256), 256, 0, stream>>>(
        rowptr, csr, hw2p, dinv, b2, out);
}

// Round 7
// 182.458 us; speedup vs baseline: 4.3219x; 1.0769x over previous
//
#include <hip/hip_runtime.h>

#define NN 100000
#define NE 1600000
#define FIN 32
#define FHID 64

#define CLB 7                                   // log2(nodes per bucket)
#define BN (1 << CLB)                           // 128 nodes / bucket
#define NB ((NN + BN - 1) / BN)                 // 782 buckets
#define NDB 256                                 // distributor blocks
#define CHUNK ((NE + NDB - 1) / NDB)            // 6250 edges / distributor block
#define NSC (NB * NDB)                          // 200192 scan elements
#define SCAN_B 1024
#define SCAN_NB ((NSC + SCAN_B - 1) / SCAN_B)   // 196

#define LGKM0 asm volatile("s_waitcnt lgkmcnt(0)" ::: "memory")

__device__ __forceinline__ float lo16(unsigned g) {
    return __uint_as_float(g << 16);
}
__device__ __forceinline__ float hi16(unsigned g) {
    return __uint_as_float(g & 0xFFFF0000u);
}
__device__ __forceinline__ unsigned pack_bf16(float a, float b) {
    unsigned ua = __float_as_uint(a);
    unsigned ub = __float_as_uint(b);
    ua += 0x7FFFu + ((ua >> 16) & 1u);          // RNE
    ub += 0x7FFFu + ((ub >> 16) & 1u);
    return (ua >> 16) | (ub & 0xFFFF0000u);
}

// ---------- pass 1: per-(bucket, block) histogram, bucket-major layout --------
__global__ void k_dcount(const int* __restrict__ col, int* __restrict__ hist_g) {
    __shared__ int hc[NB];
    for (int i = threadIdx.x; i < NB; i += blockDim.x) hc[i] = 0;
    __syncthreads();
    int beg = blockIdx.x * CHUNK, end = min(beg + CHUNK, NE);
    for (int e = beg + threadIdx.x; e < end; e += blockDim.x)
        atomicAdd(&hc[col[e] >> CLB], 1);
    __syncthreads();
    for (int i = threadIdx.x; i < NB; i += blockDim.x)
        hist_g[i * NDB + blockIdx.x] = hc[i];
}

// ---------- exclusive scan over NSC ints (3 kernels) ----------
__global__ void k_scan1(const int* __restrict__ in, int* __restrict__ out,
                        int* __restrict__ bsum) {
    __shared__ int s[SCAN_B];
    int i = blockIdx.x * SCAN_B + threadIdx.x;
    int v = (i < NSC) ? in[i] : 0;
    s[threadIdx.x] = v;
    __syncthreads();
    for (int o = 1; o < SCAN_B; o <<= 1) {
        int t = (threadIdx.x >= o) ? s[threadIdx.x - o] : 0;
        __syncthreads();
        s[threadIdx.x] += t;
        __syncthreads();
    }
    if (i < NSC) out[i] = s[threadIdx.x] - v;  // exclusive
    if (threadIdx.x == SCAN_B - 1) bsum[blockIdx.x] = s[SCAN_B - 1];
}

__global__ void k_scan2(int* __restrict__ bsum) {   // 1 block, 256 threads
    __shared__ int s[256];
    int v = (threadIdx.x < SCAN_NB) ? bsum[threadIdx.x] : 0;
    s[threadIdx.x] = v;
    __syncthreads();
    for (int o = 1; o < 256; o <<= 1) {
        int t = (threadIdx.x >= o) ? s[threadIdx.x - o] : 0;
        __syncthreads();
        s[threadIdx.x] += t;
        __syncthreads();
    }
    if (threadIdx.x < SCAN_NB) bsum[threadIdx.x] = s[threadIdx.x] - v;  // exclusive
}

__global__ void k_scan3(int* __restrict__ out, const int* __restrict__ bsum) {
    int i = blockIdx.x * blockDim.x + threadIdx.x;
    if (i < NSC) out[i] += bsum[i >> 10];
}

// ---------- pass 2: write bucketed records (no global atomics) ----------------
// record = ((col_local << 17) | src, ew_bits)
__global__ void k_dwrite(const int* __restrict__ row, const int* __restrict__ col,
                         const float* __restrict__ ew, const int* __restrict__ base_g,
                         uint2* __restrict__ rec0) {
    __shared__ int rk[NB];
    __shared__ int bl[NB];
    for (int i = threadIdx.x; i < NB; i += blockDim.x) {
        rk[i] = 0;
        bl[i] = base_g[i * NDB + blockIdx.x];
    }
    __syncthreads();
    int beg = blockIdx.x * CHUNK, end = min(beg + CHUNK, NE);
    for (int e = beg + threadIdx.x; e < end; e += blockDim.x) {
        int c = col[e];
        int bk = c >> CLB;
        int r = atomicAdd(&rk[bk], 1);
        unsigned pack = ((unsigned)(c & (BN - 1)) << 17) | (unsigned)row[e];
        rec0[bl[bk] + r] = make_uint2(pack, __float_as_uint(ew[e]));
    }
}

// ---------- per-bucket sort -> exact per-node CSR + degree/dinv ---------------
__global__ void k_bsort(const int* __restrict__ base_g, const uint2* __restrict__ rec0,
                        uint2* __restrict__ csr, int* __restrict__ rowptr,
                        float* __restrict__ dinv) {
    __shared__ int cnt[BN];
    __shared__ int bas[BN];
    __shared__ int cur[BN];
    __shared__ float dg[BN];
    int tid = threadIdx.x;
    int b = blockIdx.x;
    int beg = base_g[b * NDB];
    int end = (b == NB - 1) ? NE : base_g[(b + 1) * NDB];
    if (tid < BN) { cnt[tid] = 0; dg[tid] = 0.0f; }
    __syncthreads();
    for (int j = beg + tid; j < end; j += blockDim.x) {
        uint2 p = rec0[j];
        int cl = p.x >> 17;
        atomicAdd(&cnt[cl], 1);
        atomicAdd(&dg[cl], __uint_as_float(p.y));
    }
    __syncthreads();
    int v0 = (tid < BN) ? cnt[tid] : 0;
    __syncthreads();
    for (int o = 1; o < BN; o <<= 1) {               // Hillis-Steele inclusive
        int t = (tid < BN && tid >= o) ? cnt[tid - o] : 0;
        __syncthreads();
        if (tid < BN) cnt[tid] += t;
        __syncthreads();
    }
    if (tid < BN) {
        int excl = cnt[tid] - v0;
        bas[tid] = excl;
        cur[tid] = 0;
        int node = b * BN + tid;
        if (node < NN) {
            rowptr[node] = beg + excl;
            dinv[node] = rsqrtf(1.0f + dg[tid]);     // self-loop weight 1
        }
    }
    if (b == 0 && tid == 0) rowptr[NN] = NE;
    __syncthreads();
    for (int j = beg + tid; j < end; j += blockDim.x) {
        uint2 p = rec0[j];
        int cl = p.x >> 17;
        int r = atomicAdd(&cur[cl], 1);
        csr[beg + bas[cl] + r] = make_uint2(p.x & 0x1FFFFu, p.y);
    }
}

// ---------- xp = bf16x2-packed dinv*x ----------------------------------------
__global__ void k_scalex(const float* __restrict__ x, const float* __restrict__ dinv,
                         unsigned* __restrict__ xp) {
    int idx = blockIdx.x * blockDim.x + threadIdx.x;   // pair index
    if (idx >= NN * (FIN / 2)) return;
    float dn = dinv[idx >> 4];
    float2 v = ((const float2*)x)[idx];
    xp[idx] = pack_bf16(v.x * dn, v.y * dn);
}

// ---------- layer 1 fused: agg + GEMM1(+b1,relu) + GEMM2 + dinv  -> hw2p ------
// Wave layout: slot s = lane>>3 owns edge j = beg+s (step 8);
// u = lane&7 owns feature quad (4u..4u+3) as uint2 of bf16x2.
__global__ __launch_bounds__(256) void k_agg1f(
        const int* __restrict__ rowptr, const uint2* __restrict__ csr,
        const uint2* __restrict__ xp2, const float* __restrict__ dinv,
        const float* __restrict__ W1, const float* __restrict__ b1,
        const float* __restrict__ W2, unsigned* __restrict__ hw2p, int nwaves) {
    __shared__ float pre_lds[4 * FIN];
    __shared__ float hv_lds[4 * FHID];
    int lane = threadIdx.x & 63;
    int ws = threadIdx.x >> 6;          // wave slot in block
    int s = lane >> 3;                  // edge slot 0..7
    int u = lane & 7;                   // feature-quad index
    int hh = lane >> 5;
    int f = lane & 31;
    int t = lane & 15;
    int o = lane;                       // 0..63
    // register-resident weights
    float W1col[FIN];
#pragma unroll
    for (int k = 0; k < FIN; ++k) W1col[k] = W1[k * FHID + o];
    float b1o = b1[o];
    float W2h[FIN];
#pragma unroll
    for (int k = 0; k < FIN; ++k) W2h[k] = W2[(hh * 32 + k) * FIN + f];

    int gw = (blockIdx.x * blockDim.x + threadIdx.x) >> 6;
    for (int n = gw; n < NN; n += nwaves) {
        int beg = rowptr[n], end = rowptr[n + 1];
        float c0 = 0.0f, c1 = 0.0f, c2 = 0.0f, c3 = 0.0f;
        float d0 = 0.0f, d1 = 0.0f, d2 = 0.0f, d3 = 0.0f;
        int j = beg + s;
        for (; j + 8 < end; j += 16) {
            uint2 e0 = csr[j];
            uint2 e1 = csr[j + 8];
            uint2 g0 = xp2[(size_t)e0.x * 8 + u];
            uint2 g1 = xp2[(size_t)e1.x * 8 + u];
            float w0 = __uint_as_float(e0.y);
            float w1 = __uint_as_float(e1.y);
            c0 = fmaf(w0, lo16(g0.x), c0);
            c1 = fmaf(w0, hi16(g0.x), c1);
            c2 = fmaf(w0, lo16(g0.y), c2);
            c3 = fmaf(w0, hi16(g0.y), c3);
            d0 = fmaf(w1, lo16(g1.x), d0);
            d1 = fmaf(w1, hi16(g1.x), d1);
            d2 = fmaf(w1, lo16(g1.y), d2);
            d3 = fmaf(w1, hi16(g1.y), d3);
        }
        for (; j < end; j += 8) {
            uint2 e = csr[j];
            uint2 g = xp2[(size_t)e.x * 8 + u];
            float w = __uint_as_float(e.y);
            c0 = fmaf(w, lo16(g.x), c0);
            c1 = fmaf(w, hi16(g.x), c1);
            c2 = fmaf(w, lo16(g.y), c2);
            c3 = fmaf(w, hi16(g.y), c3);
        }
        c0 += d0; c1 += d1; c2 += d2; c3 += d3;
        // reduce across 8 slots (lane bits 3,4,5)
#pragma unroll
        for (int m = 8; m <= 32; m <<= 1) {
            c0 += __shfl_xor(c0, m, 64);
            c1 += __shfl_xor(c1, m, 64);
            c2 += __shfl_xor(c2, m, 64);
            c3 += __shfl_xor(c3, m, 64);
        }
        float dn = dinv[n];
        uint2 gs = xp2[(size_t)n * 8 + u];
        if (s == 0) {
            float4 pq;
            pq.x = dn * (c0 + lo16(gs.x));
            pq.y = dn * (c1 + hi16(gs.x));
            pq.z = dn * (c2 + lo16(gs.y));
            pq.w = dn * (c3 + hi16(gs.y));
            *(float4*)&pre_lds[ws * FIN + 4 * u] = pq;
        }
        LGKM0;
        // GEMM1: h_o = relu(b1 + sum_k pre[k] * W1[k][o])
        float hacc = b1o;
#pragma unroll
        for (int i = 0; i < 8; ++i) {
            float4 qd = *(const float4*)&pre_lds[ws * FIN + 4 * i];
            hacc = fmaf(qd.x, W1col[4 * i + 0], hacc);
            hacc = fmaf(qd.y, W1col[4 * i + 1], hacc);
            hacc = fmaf(qd.z, W1col[4 * i + 2], hacc);
            hacc = fmaf(qd.w, W1col[4 * i + 3], hacc);
        }
        hacc = hacc > 0.0f ? hacc : 0.0f;
        hv_lds[ws * FHID + o] = hacc;
        LGKM0;
        // GEMM2 (halves split o-range): v[f] = dn * sum_o h_o W2[o][f]
        float part = 0.0f;
#pragma unroll
        for (int i = 0; i < 8; ++i) {
            float4 qd = *(const float4*)&hv_lds[ws * FHID + hh * 32 + 4 * i];
            part = fmaf(qd.x, W2h[4 * i + 0], part);
            part = fmaf(qd.y, W2h[4 * i + 1], part);
            part = fmaf(qd.z, W2h[4 * i + 2], part);
            part = fmaf(qd.w, W2h[4 * i + 3], part);
        }
        part += __shfl_xor(part, 32, 64);    // all lanes: final v for f=lane&31
        float v = dn * part;
        float vlo = __shfl(v, 2 * t, 64);
        float vhi = __shfl(v, 2 * t + 1, 64);
        if (lane < 16) hw2p[(size_t)n * 16 + lane] = pack_bf16(vlo, vhi);
    }
}

// ---------- layer 2 aggregation + bias + relu -> out --------------------------
__global__ __launch_bounds__(256) void k_agg2(
        const int* __restrict__ rowptr, const uint2* __restrict__ csr,
        const uint2* __restrict__ hw2p2, const float* __restrict__ dinv,
        const float* __restrict__ b2, float* __restrict__ out) {
    int n = (blockIdx.x * blockDim.x + threadIdx.x) >> 6;
    if (n >= NN) return;
    int lane = threadIdx.x & 63;
    int s = lane >> 3;
    int u = lane & 7;
    float4 b2q = ((const float4*)b2)[u];
    int beg = rowptr[n], end = rowptr[n + 1];
    float c0 = 0.0f, c1 = 0.0f, c2 = 0.0f, c3 = 0.0f;
    float d0 = 0.0f, d1 = 0.0f, d2 = 0.0f, d3 = 0.0f;
    int j = beg + s;
    for (; j + 8 < end; j += 16) {
        uint2 e0 = csr[j];
        uint2 e1 = csr[j + 8];
        uint2 g0 = hw2p2[(size_t)e0.x * 8 + u];
        uint2 g1 = hw2p2[(size_t)e1.x * 8 + u];
        float w0 = __uint_as_float(e0.y);
        float w1 = __uint_as_float(e1.y);
        c0 = fmaf(w0, lo16(g0.x), c0);
        c1 = fmaf(w0, hi16(g0.x), c1);
        c2 = fmaf(w0, lo16(g0.y), c2);
        c3 = fmaf(w0, hi16(g0.y), c3);
        d0 = fmaf(w1, lo16(g1.x), d0);
        d1 = fmaf(w1, hi16(g1.x), d1);
        d2 = fmaf(w1, lo16(g1.y), d2);
        d3 = fmaf(w1, hi16(g1.y), d3);
    }
    for (; j < end; j += 8) {
        uint2 e = csr[j];
        uint2 g = hw2p2[(size_t)e.x * 8 + u];
        float w = __uint_as_float(e.y);
        c0 = fmaf(w, lo16(g.x), c0);
        c1 = fmaf(w, hi16(g.x), c1);
        c2 = fmaf(w, lo16(g.y), c2);
        c3 = fmaf(w, hi16(g.y), c3);
    }
    c0 += d0; c1 += d1; c2 += d2; c3 += d3;
#pragma unroll
    for (int m = 8; m <= 32; m <<= 1) {
        c0 += __shfl_xor(c0, m, 64);
        c1 += __shfl_xor(c1, m, 64);
        c2 += __shfl_xor(c2, m, 64);
        c3 += __shfl_xor(c3, m, 64);
    }
    if (s == 0) {
        float dn = dinv[n];
        uint2 gs = hw2p2[(size_t)n * 8 + u];
        float4 v;
        v.x = dn * (c0 + lo16(gs.x)) + b2q.x;
        v.y = dn * (c1 + hi16(gs.x)) + b2q.y;
        v.z = dn * (c2 + lo16(gs.y)) + b2q.z;
        v.w = dn * (c3 + hi16(gs.y)) + b2q.w;
        v.x = v.x > 0.0f ? v.x : 0.0f;
        v.y = v.y > 0.0f ? v.y : 0.0f;
        v.z = v.z > 0.0f ? v.z : 0.0f;
        v.w = v.w > 0.0f ? v.w : 0.0f;
        ((float4*)out)[(size_t)n * 8 + u] = v;
    }
}

extern "C" void kernel_launch(void* const* d_in, const int* in_sizes, int n_in,
                              void* d_out, int out_size, void* d_ws, size_t ws_size,
                              hipStream_t stream) {
    const float* x  = (const float*)d_in[0];
    const int*   ei = (const int*)d_in[1];
    const float* ea = (const float*)d_in[2];
    const float* W1 = (const float*)d_in[3];
    const float* b1 = (const float*)d_in[4];
    const float* W2 = (const float*)d_in[5];
    const float* b2 = (const float*)d_in[6];
    float* out = (float*)d_out;

    const int* row = ei;        // edge_index[0]
    const int* col = ei + NE;   // edge_index[1]

    // workspace layout (~41 MB)
    char* w = (char*)d_ws;
    uint2* rec0     = (uint2*)w;                         // NE*8
    uint2* csr      = rec0 + NE;                         // NE*8
    unsigned* xp    = (unsigned*)(csr + NE);             // NN*16 (bf16x2)
    unsigned* hw2p  = xp + (size_t)NN * 16;              // NN*16 (bf16x2)
    float* dinv     = (float*)(hw2p + (size_t)NN * 16);  // NN
    int*   rowptr   = (int*)(dinv + NN);                 // NN+1
    int*   hist_g   = rowptr + NN + 1;                   // NSC
    int*   scng     = hist_g + NSC;                      // NSC
    int*   bsum     = scng + NSC;                        // 256

    auto cdiv = [](long long a, int b) { return (int)((a + b - 1) / b); };

    // independent: edge_attr passthrough
    hipMemcpyAsync(out + (size_t)NN * FIN, ea, sizeof(float) * (size_t)NE,
                   hipMemcpyDeviceToDevice, stream);

    // deterministic counting-sort build (no global atomics)
    k_dcount<<<NDB, 256, 0, stream>>>(col, hist_g);
    k_scan1<<<SCAN_NB, SCAN_B, 0, stream>>>(hist_g, scng, bsum);
    k_scan2<<<1, 256, 0, stream>>>(bsum);
    k_scan3<<<cdiv(NSC, 256), 256, 0, stream>>>(scng, bsum);
    k_dwrite<<<NDB, 256, 0, stream>>>(row, col, ea, scng, rec0);
    k_bsort<<<NB, 256, 0, stream>>>(scng, rec0, csr, rowptr, dinv);

    // fold src-side norm into x, pack bf16x2
    k_scalex<<<cdiv((long long)NN * (FIN / 2), 256), 256, 0, stream>>>(x, dinv, xp);

    // layer 1 fused (agg + GEMM1 + GEMM2 + dst scale) -> hw2p (bf16x2)
    const int A1_BLOCKS = 2048;
    k_agg1f<<<A1_BLOCKS, 256, 0, stream>>>(rowptr, csr, (const uint2*)xp, dinv,
                                           W1, b1, W2, hw2p, A1_BLOCKS * 4);

    // layer 2 aggregation -> out
    k_agg2<<<cdiv((long long)NN * 64, 256), 256, 0, stream>>>(
        rowptr, csr, (const uint2*)hw2p, dinv, b2, out);
}